// Round 16
// baseline (320.579 us; speedup 1.0000x reference)
//
#include <hip/hip_runtime.h>
#include <math.h>

#define N_NODES 100000
#define D 128
#define N_EDGES 1600000
#define BN_EPS 1e-5f
#define SCAN_NB 200
#define SCAN_BC 500    // elements per scan block; 200*500 = 100000 exact
#define EG_BLOCKS 1563 // ceil(N_EDGES / 1024); hist & scatter: 4 edges/thread
#define GEMM_BLOCKS 1563 // ceil(N_NODES / 64)
#define NCOPY 32       // counter copies; 32 = 4 per XCD, cuts L2 line-lock serialization 4x vs 8

typedef __attribute__((ext_vector_type(8))) short bf16x8;
typedef __attribute__((ext_vector_type(4))) float f32x4;

__device__ inline unsigned short f2bf(float f) {
    unsigned int u = __float_as_uint(f);
    unsigned int r = u + 0x7FFFu + ((u >> 16) & 1u);
    return (unsigned short)(r >> 16);
}
__device__ inline float bf2f(unsigned short b) {
    return __uint_as_float(((unsigned int)b) << 16);
}

// ============ FUSED: bn_stats (blocks 0..255) || hist_rank (blocks 256..1818) ======
// hist: 1563 blocks x 4 edges/thread. Copy = b&31 (edge i -> (i>>10)&31): block
// 256+k -> XCD k%8, copy k&31 -> XCD (k&31)%8 fixed per copy => each copy's lines
// stay in ONE XCD L2. 32 copies cut per-line atomic collisions 4x vs 8 copies
// (R15 theory: wall = L2 per-line RMW serialization, invariant to waves/shape).
__global__ __launch_bounds__(256)
void stats_hist(const float* __restrict__ x, float* __restrict__ sums,
                const int* __restrict__ src, int* __restrict__ cnt,
                int* __restrict__ rank) {
    if (blockIdx.x < 256) {
        const int col  = threadIdx.x & 127;
        const int half = threadIdx.x >> 7;
        float s = 0.f, sq = 0.f;
        for (int r = blockIdx.x * 2 + half; r < N_NODES; r += 512) {
            float v = x[(size_t)r * D + col];
            s += v; sq += v * v;
        }
        __shared__ float ls[2][128];
        __shared__ float lq[2][128];
        ls[half][col] = s; lq[half][col] = sq;
        __syncthreads();
        if (threadIdx.x < 128) {
            atomicAdd(&sums[col],       ls[0][col] + ls[1][col]);
            atomicAdd(&sums[128 + col], lq[0][col] + lq[1][col]);
        }
    } else {
        const int b = blockIdx.x - 256;
        int* c = cnt + (size_t)(b & (NCOPY - 1)) * N_NODES;
        const int base = b * 1024 + threadIdx.x;
#pragma unroll
        for (int k = 0; k < 4; ++k) {
            int i = base + k * 256;
            if (i < N_EDGES) rank[i] = atomicAdd(&c[src[i]], 1);
        }
    }
}

// ============ FUSED: bn_finalize (block 0) || pack_weights (blocks 1..24) ==========
__global__ __launch_bounds__(256)
void finalize_pack(const float* __restrict__ sums, const float* __restrict__ gamma,
                   const float* __restrict__ beta, float* __restrict__ scale,
                   float* __restrict__ bias,
                   const float* __restrict__ k0, const float* __restrict__ k1,
                   const float* __restrict__ k2, unsigned short* __restrict__ wpack) {
    if (blockIdx.x == 0) {
        if (threadIdx.x < 128) {
            int c = threadIdx.x;
            float mean = sums[c] * (1.0f / N_NODES);
            float var  = sums[128 + c] * (1.0f / N_NODES) - mean * mean;
            float rstd = rsqrtf(var + BN_EPS);
            float sc = gamma[c] * rstd;
            scale[c] = sc;
            bias[c]  = beta[c] - mean * sc;
        }
        return;
    }
    int idx = (blockIdx.x - 1) * 256 + threadIdx.x;   // one 8-elem fragment each
    if (idx >= 3 * 4 * 8 * 64) return;                // 6144
    int m    = idx >> 11;
    int r    = idx & 2047;
    int kk   = r >> 9;
    int r2   = r & 511;
    int nt   = r2 >> 6;
    int lane = r2 & 63;
    const float* W = (m == 0) ? k0 : (m == 1) ? k1 : k2;
    int col   = nt * 16 + (lane & 15);
    int kbase = kk * 32 + (lane >> 4) * 8;
    unsigned int wh[4], wl[4];
#pragma unroll
    for (int i = 0; i < 4; ++i) {
        float a = W[(kbase + 2 * i)     * 128 + col];
        float b = W[(kbase + 2 * i + 1) * 128 + col];
        unsigned short ah = f2bf(a), bh = f2bf(b);
        unsigned short al = f2bf(a - bf2f(ah)), bl = f2bf(b - bf2f(bh));
        wh[i] = (unsigned int)ah | ((unsigned int)bh << 16);
        wl[i] = (unsigned int)al | ((unsigned int)bl << 16);
    }
    uint4* outp = (uint4*)wpack;
    outp[idx]        = make_uint4(wh[0], wh[1], wh[2], wh[3]);
    outp[6144 + idx] = make_uint4(wl[0], wl[1], wl[2], wl[3]);
}

// ---------------- hierarchical scan, phase A: per-block sums over NCOPY copies -----
__global__ __launch_bounds__(256)
void scan_blocksum(const int* __restrict__ cnt, int* __restrict__ bsum) {
    __shared__ int red[256];
    const int b = blockIdx.x, t = threadIdx.x;
    const int base = b * SCAN_BC;
    int s = 0;
    for (int i = t; i < SCAN_BC; i += 256) {
        int node = base + i;
        for (int x = 0; x < NCOPY; ++x) s += cnt[(size_t)x * N_NODES + node];
    }
    red[t] = s;
    __syncthreads();
    for (int off = 128; off; off >>= 1) {
        if (t < off) red[t] += red[t + off];
        __syncthreads();
    }
    if (t == 0) bsum[b] = red[0];
}

// ---------------- phase B: exclusive scan of the 200 block sums ----------------
__global__ __launch_bounds__(256)
void scan_bases(int* __restrict__ bsum, int* __restrict__ row_off) {
    __shared__ int v[256];
    const int t = threadIdx.x;
    v[t] = (t < SCAN_NB) ? bsum[t] : 0;
    __syncthreads();
    for (int off = 1; off < 256; off <<= 1) {
        int u = (t >= off) ? v[t - off] : 0;
        __syncthreads();
        v[t] += u;
        __syncthreads();
    }
    if (t < SCAN_NB) bsum[t] = (t == 0) ? 0 : v[t - 1];
    if (t == 0) row_off[N_NODES] = v[SCAN_NB - 1];
}

// ---------------- phase C: scan + write row_off; rewrite cnt[x][s] -> segment base -
__global__ __launch_bounds__(256)
void scan_write(int* __restrict__ cnt, const int* __restrict__ bsum,
                int* __restrict__ row_off) {
    __shared__ int tsum[256];
    const int b = blockIdx.x, t = threadIdx.x;
    const int i0 = b * SCAN_BC + t * 2;   // t < 250 covers the 500-elem chunk
    int tot0 = 0, tot1 = 0;
    if (t < 250) {
        for (int x = 0; x < NCOPY; ++x) {
            tot0 += cnt[(size_t)x * N_NODES + i0];
            tot1 += cnt[(size_t)x * N_NODES + i0 + 1];
        }
    }
    tsum[t] = tot0 + tot1;
    __syncthreads();
    for (int off = 1; off < 256; off <<= 1) {
        int u = (t >= off) ? tsum[t - off] : 0;
        __syncthreads();
        tsum[t] += u;
        __syncthreads();
    }
    if (t < 250) {
        int run = bsum[b] + ((t == 0) ? 0 : tsum[t - 1]);
        row_off[i0] = run;
        int acc = run;
        for (int x = 0; x < NCOPY; ++x) {
            size_t idx = (size_t)x * N_NODES + i0;
            int v = cnt[idx];
            cnt[idx] = acc; acc += v;
        }
        run += tot0;
        row_off[i0 + 1] = run;
        acc = run;
        for (int x = 0; x < NCOPY; ++x) {
            size_t idx = (size_t)x * N_NODES + i0 + 1;
            int v = cnt[idx];
            cnt[idx] = acc; acc += v;
        }
    }
}

// ============ FUSED: gemm_mfma (blocks 0..1562) || scatter_edges (1563..) ==========
// scatter copy selector: b&31 == (i>>10)&31, matching the 1024-edge hist windows.
__global__ __launch_bounds__(256, 4)
void gemm_scatter(const float* __restrict__ x, const unsigned short* __restrict__ wpack,
                  const float* __restrict__ scale, const float* __restrict__ bias,
                  unsigned short* __restrict__ mapped, float* __restrict__ s1,
                  float* __restrict__ s2,
                  const int* __restrict__ src, const int* __restrict__ dst,
                  const int* __restrict__ cnt, const int* __restrict__ rank,
                  int* __restrict__ dst_sorted) {
    __shared__ unsigned short xbuf[64 * 128];   // 16 KB, XOR-swizzled rows
    if (blockIdx.x >= GEMM_BLOCKS) {
        // ---- scatter path (atomic-free) ----
        const int b = blockIdx.x - GEMM_BLOCKS;
        const int* c = cnt + (size_t)(b & (NCOPY - 1)) * N_NODES;
        const int base = b * 1024 + threadIdx.x;
#pragma unroll
        for (int k = 0; k < 4; ++k) {
            int i = base + k * 256;
            if (i < N_EDGES) dst_sorted[c[src[i]] + rank[i]] = dst[i];
        }
        return;
    }
    // ---- gemm path (R10-proven: time-shared 16KB LDS, 3 barriers) ----
    const int tid  = threadIdx.x;
    const int wave = tid >> 6, lane = tid & 63;
    const int base = blockIdx.x * 64;
    char* xb = (char*)xbuf;

    float2 sc = ((const float2*)scale)[lane];
    float2 bs = ((const float2*)bias)[lane];

    // phase 1: stage LO into LDS; keep HI packed in registers
    unsigned int hipack[16];
#pragma unroll
    for (int rr = 0; rr < 16; ++rr) {
        int row  = wave * 16 + rr;
        int node = base + row;
        float2 v = make_float2(0.f, 0.f);
        if (node < N_NODES) v = ((const float2*)x)[(size_t)node * 64 + lane];
        float f0 = v.x * sc.x + bs.x;
        float f1 = v.y * sc.y + bs.y;
        unsigned short h0 = f2bf(f0), h1 = f2bf(f1);
        unsigned short l0 = f2bf(f0 - bf2f(h0)), l1 = f2bf(f1 - bf2f(h1));
        hipack[rr] = (unsigned int)h0 | ((unsigned int)h1 << 16);
        int byte = (row * 256 + lane * 4) ^ ((row & 7) << 4);
        *(unsigned int*)(xb + byte) = (unsigned int)l0 | ((unsigned int)l1 << 16);
    }
    __syncthreads();   // W_lo -> R_lo (cross-lane RAW)

    const int arow  = wave * 16 + (lane & 15);
    const int lrow0 = wave * 16 + (lane >> 4) * 4;

    bf16x8 al[4];
#pragma unroll
    for (int kk = 0; kk < 4; ++kk) {
        int byte = (arow * 256 + kk * 64 + (lane >> 4) * 16) ^ ((arow & 7) << 4);
        al[kk] = *(const bf16x8*)(xb + byte);
    }
    unsigned int xlo[16];
#pragma unroll
    for (int nt = 0; nt < 8; ++nt) {
#pragma unroll
        for (int reg = 0; reg < 4; ++reg) {
            int lrow = lrow0 + reg;
            int col  = nt * 16 + (lane & 15);
            int byte = (lrow * 256 + col * 2) ^ ((lrow & 7) << 4);
            unsigned short v = *(const unsigned short*)(xb + byte);
            int idx = nt * 4 + reg;
            if (idx & 1) xlo[idx >> 1] |= ((unsigned int)v) << 16;
            else         xlo[idx >> 1]  = v;
        }
    }
    __syncthreads();   // R_lo -> W_hi (cross-lane WAR)

    // phase 2: overwrite LDS slice with HI
#pragma unroll
    for (int rr = 0; rr < 16; ++rr) {
        int row  = wave * 16 + rr;
        int byte = (row * 256 + lane * 4) ^ ((row & 7) << 4);
        *(unsigned int*)(xb + byte) = hipack[rr];
    }
    __syncthreads();   // W_hi -> R_hi (cross-lane RAW)

    bf16x8 ah[4];
#pragma unroll
    for (int kk = 0; kk < 4; ++kk) {
        int byte = (arow * 256 + kk * 64 + (lane >> 4) * 16) ^ ((arow & 7) << 4);
        ah[kk] = *(const bf16x8*)(xb + byte);
    }

    const bf16x8* wp = (const bf16x8*)wpack;   // hi: [0,6144) frags; lo: +6144

    // matrix 0 -> mapped (hi-only precision, bf16 store)
    {
        f32x4 acc[8] = {};
#pragma unroll
        for (int kk = 0; kk < 4; ++kk) {
#pragma unroll
            for (int nt = 0; nt < 8; ++nt) {
                bf16x8 b = wp[(kk * 8 + nt) * 64 + lane];
                acc[nt] = __builtin_amdgcn_mfma_f32_16x16x32_bf16(ah[kk], b, acc[nt], 0, 0, 0);
            }
        }
        int crow = base + wave * 16 + (lane >> 4) * 4;
        int ccol = lane & 15;
#pragma unroll
        for (int nt = 0; nt < 8; ++nt) {
#pragma unroll
            for (int reg = 0; reg < 4; ++reg) {
                int node = crow + reg;
                if (node < N_NODES)
                    mapped[(size_t)node * 128 + nt * 16 + ccol] = f2bf(acc[nt][reg]);
            }
        }
    }

    // matrices 1,2 (split precision) -> per-row dot with xn -> s1,s2
    {
        float p1[4] = {0.f, 0.f, 0.f, 0.f};
        float p2[4] = {0.f, 0.f, 0.f, 0.f};
#pragma unroll
        for (int nt = 0; nt < 8; ++nt) {
            f32x4 a1 = {0.f, 0.f, 0.f, 0.f};
            f32x4 a2 = {0.f, 0.f, 0.f, 0.f};
#pragma unroll
            for (int kk = 0; kk < 4; ++kk) {
                int fi = (kk * 8 + nt) * 64 + lane;
                bf16x8 b1h = wp[2048 * 1 + fi];
                bf16x8 b1l = wp[6144 + 2048 * 1 + fi];
                bf16x8 b2h = wp[2048 * 2 + fi];
                bf16x8 b2l = wp[6144 + 2048 * 2 + fi];
                a1 = __builtin_amdgcn_mfma_f32_16x16x32_bf16(ah[kk], b1h, a1, 0, 0, 0);
                a1 = __builtin_amdgcn_mfma_f32_16x16x32_bf16(al[kk], b1h, a1, 0, 0, 0);
                a1 = __builtin_amdgcn_mfma_f32_16x16x32_bf16(ah[kk], b1l, a1, 0, 0, 0);
                a2 = __builtin_amdgcn_mfma_f32_16x16x32_bf16(ah[kk], b2h, a2, 0, 0, 0);
                a2 = __builtin_amdgcn_mfma_f32_16x16x32_bf16(al[kk], b2h, a2, 0, 0, 0);
                a2 = __builtin_amdgcn_mfma_f32_16x16x32_bf16(ah[kk], b2l, a2, 0, 0, 0);
            }
            int col = nt * 16 + (lane & 15);
#pragma unroll
            for (int reg = 0; reg < 4; ++reg) {
                int lrow = lrow0 + reg;
                int byte = (lrow * 256 + col * 2) ^ ((lrow & 7) << 4);
                float xh = bf2f(*(const unsigned short*)(xb + byte));
                int idx = nt * 4 + reg;
                unsigned short lo16 = (idx & 1) ? (unsigned short)(xlo[idx >> 1] >> 16)
                                                : (unsigned short)(xlo[idx >> 1] & 0xFFFFu);
                float xv = xh + bf2f(lo16);
                p1[reg] = fmaf(a1[reg], xv, p1[reg]);
                p2[reg] = fmaf(a2[reg], xv, p2[reg]);
            }
        }
#pragma unroll
        for (int reg = 0; reg < 4; ++reg) {
#pragma unroll
            for (int off = 1; off < 16; off <<= 1) {
                p1[reg] += __shfl_xor(p1[reg], off);
                p2[reg] += __shfl_xor(p2[reg], off);
            }
        }
        if ((lane & 15) == 0) {
            int nbase = base + wave * 16 + (lane >> 4) * 4;
#pragma unroll
            for (int reg = 0; reg < 4; ++reg) {
                int node = nbase + reg;
                if (node < N_NODES) {
                    s1[node] = tanhf(p1[reg]);
                    s2[node] = tanhf(p2[reg]);
                }
            }
        }
    }
}

// ---------------- per-node (1 wave): inline score + softmax + gather + relu --------
__global__ __launch_bounds__(256)
void node_aggregate(const int* __restrict__ row_off, const int* __restrict__ dst_sorted,
                    const float* __restrict__ s1, const float* __restrict__ s2,
                    const unsigned int* __restrict__ mapped,
                    float* __restrict__ out) {
    const int wave = threadIdx.x >> 6, lane = threadIdx.x & 63;
    const int n = blockIdx.x * 4 + wave;
    if (n >= N_NODES) return;
    const int beg = row_off[n], end = row_off[n + 1];
    const int deg = end - beg;
    float acc0 = 0.f, acc1 = 0.f, den = 0.f;

#define GATHER8(WSRC, DSRC, J)                                                   \
    {                                                                            \
        float w0 = __shfl(WSRC, (J) + 0), w1 = __shfl(WSRC, (J) + 1);            \
        float w2 = __shfl(WSRC, (J) + 2), w3 = __shfl(WSRC, (J) + 3);            \
        float w4 = __shfl(WSRC, (J) + 4), w5 = __shfl(WSRC, (J) + 5);            \
        float w6 = __shfl(WSRC, (J) + 6), w7 = __shfl(WSRC, (J) + 7);            \
        int d0 = __shfl(DSRC, (J) + 0), d1 = __shfl(DSRC, (J) + 1);              \
        int d2 = __shfl(DSRC, (J) + 2), d3 = __shfl(DSRC, (J) + 3);              \
        int d4 = __shfl(DSRC, (J) + 4), d5 = __shfl(DSRC, (J) + 5);              \
        int d6 = __shfl(DSRC, (J) + 6), d7 = __shfl(DSRC, (J) + 7);              \
        unsigned int m0 = mapped[(size_t)d0 * 64 + lane];                        \
        unsigned int m1 = mapped[(size_t)d1 * 64 + lane];                        \
        unsigned int m2 = mapped[(size_t)d2 * 64 + lane];                        \
        unsigned int m3 = mapped[(size_t)d3 * 64 + lane];                        \
        unsigned int m4 = mapped[(size_t)d4 * 64 + lane];                        \
        unsigned int m5 = mapped[(size_t)d5 * 64 + lane];                        \
        unsigned int m6 = mapped[(size_t)d6 * 64 + lane];                        \
        unsigned int m7 = mapped[(size_t)d7 * 64 + lane];                        \
        acc0 = fmaf(w0, bf2f((unsigned short)(m0 & 0xFFFFu)), acc0);             \
        acc1 = fmaf(w0, bf2f((unsigned short)(m0 >> 16)), acc1);                 \
        acc0 = fmaf(w1, bf2f((unsigned short)(m1 & 0xFFFFu)), acc0);             \
        acc1 = fmaf(w1, bf2f((unsigned short)(m1 >> 16)), acc1);                 \
        acc0 = fmaf(w2, bf2f((unsigned short)(m2 & 0xFFFFu)), acc0);             \
        acc1 = fmaf(w2, bf2f((unsigned short)(m2 >> 16)), acc1);                 \
        acc0 = fmaf(w3, bf2f((unsigned short)(m3 & 0xFFFFu)), acc0);             \
        acc1 = fmaf(w3, bf2f((unsigned short)(m3 >> 16)), acc1);                 \
        acc0 = fmaf(w4, bf2f((unsigned short)(m4 & 0xFFFFu)), acc0);             \
        acc1 = fmaf(w4, bf2f((unsigned short)(m4 >> 16)), acc1);                 \
        acc0 = fmaf(w5, bf2f((unsigned short)(m5 & 0xFFFFu)), acc0);             \
        acc1 = fmaf(w5, bf2f((unsigned short)(m5 >> 16)), acc1);                 \
        acc0 = fmaf(w6, bf2f((unsigned short)(m6 & 0xFFFFu)), acc0);             \
        acc1 = fmaf(w6, bf2f((unsigned short)(m6 >> 16)), acc1);                 \
        acc0 = fmaf(w7, bf2f((unsigned short)(m7 & 0xFFFFu)), acc0);             \
        acc1 = fmaf(w7, bf2f((unsigned short)(m7 >> 16)), acc1);                 \
    }

    if (deg > 0 && deg <= 64) {
        float s1n = s1[n];
        int   d_l = 0; float e_l = -INFINITY;
        if (lane < deg) {
            d_l = dst_sorted[beg + lane];
            float v = s1n + s2[d_l];
            e_l = v > 0.f ? v : 0.01f * v;
        }
        float m = e_l;
#pragma unroll
        for (int off = 1; off < 64; off <<= 1) m = fmaxf(m, __shfl_xor(m, off));
        float w_l = (lane < deg) ? expf(e_l - m) : 0.f;
        den = w_l;
        int j = 0;
        for (; j + 8 <= deg; j += 8) GATHER8(w_l, d_l, j)
        for (; j < deg; ++j) {
            float wj = __shfl(w_l, j);
            int   dj = __shfl(d_l, j);
            unsigned int mv = mapped[(size_t)dj * 64 + lane];
            acc0 = fmaf(wj, bf2f((unsigned short)(mv & 0xFFFFu)), acc0);
            acc1 = fmaf(wj, bf2f((unsigned short)(mv >> 16)), acc1);
        }
    } else if (deg > 64) {
        float s1n = s1[n];
        float m = -INFINITY;
        for (int chunk = beg; chunk < end; chunk += 64) {
            if (chunk + lane < end) {
                int dj = dst_sorted[chunk + lane];
                float v = s1n + s2[dj];
                m = fmaxf(m, v > 0.f ? v : 0.01f * v);
            }
        }
#pragma unroll
        for (int off = 1; off < 64; off <<= 1) m = fmaxf(m, __shfl_xor(m, off));
        for (int chunk = beg; chunk < end; chunk += 64) {
            int nc = min(64, end - chunk);
            int   d_l = 0; float w_l = 0.f;
            if (lane < nc) {
                d_l = dst_sorted[chunk + lane];
                float v = s1n + s2[d_l];
                float e = v > 0.f ? v : 0.01f * v;
                w_l = expf(e - m);
            }
            den += w_l;
            int j = 0;
            for (; j + 8 <= nc; j += 8) GATHER8(w_l, d_l, j)
            for (; j < nc; ++j) {
                float wj = __shfl(w_l, j);
                int   dj = __shfl(d_l, j);
                unsigned int mv = mapped[(size_t)dj * 64 + lane];
                acc0 = fmaf(wj, bf2f((unsigned short)(mv & 0xFFFFu)), acc0);
                acc1 = fmaf(wj, bf2f((unsigned short)(mv >> 16)), acc1);
            }
        }
    }
#undef GATHER8

    if (deg > 0) {
#pragma unroll
        for (int off = 1; off < 64; off <<= 1) den += __shfl_xor(den, off);
        float inv = 1.f / fmaxf(den, 1e-16f);
        acc0 *= inv; acc1 *= inv;
    }
    ((float2*)out)[(size_t)n * 64 + lane] = make_float2(fmaxf(acc0, 0.f), fmaxf(acc1, 0.f));
}

extern "C" void kernel_launch(void* const* d_in, const int* in_sizes, int n_in,
                              void* d_out, int out_size, void* d_ws, size_t ws_size,
                              hipStream_t stream) {
    const float* x     = (const float*)d_in[0];
    const int*   ei    = (const int*)d_in[1];   // [2][E]: row0 = src, row1 = dst
    const float* k0    = (const float*)d_in[2];
    const float* k1    = (const float*)d_in[3];
    const float* k2    = (const float*)d_in[4];
    const float* gamma = (const float*)d_in[5];
    const float* beta  = (const float*)d_in[6];
    float* out = (float*)d_out;

    const int* src = ei;
    const int* dst = ei + N_EDGES;

    char* ws = (char*)d_ws;
    unsigned short* wpack = (unsigned short*)ws;           ws += 6 * 128 * 128 * 2; // hi+lo
    float* s1       = (float*)ws;                          ws += N_NODES * 4;
    float* s2       = (float*)ws;                          ws += N_NODES * 4;
    float* scale    = (float*)ws;                          ws += 128 * 4;
    float* bias     = (float*)ws;                          ws += 128 * 4;
    float* sums     = (float*)ws;                          ws += 256 * 4;
    int*   bsum     = (int*)ws;                            ws += 256 * 4;
    int*   row_off  = (int*)ws;                            ws += (N_NODES + 1) * 4;
    int*   cnt      = (int*)ws;                            ws += (size_t)NCOPY * N_NODES * 4;
    int*   rank     = (int*)ws;                            ws += (size_t)N_EDGES * 4;
    int*   dst_sorted = (int*)ws;                          ws += (size_t)N_EDGES * 4;
    unsigned short* mapped = (unsigned short*)ws;          ws += (size_t)N_NODES * D * 2;

    // zero accumulators (harness does not re-poison between replays)
    hipMemsetAsync(sums, 0, 256 * sizeof(float), stream);
    hipMemsetAsync(cnt, 0, (size_t)NCOPY * N_NODES * sizeof(int), stream);

    stats_hist<<<256 + EG_BLOCKS, 256, 0, stream>>>(x, sums, src, cnt, rank);
    finalize_pack<<<25, 256, 0, stream>>>(sums, gamma, beta, scale, bias,
                                          k0, k1, k2, wpack);
    scan_blocksum<<<SCAN_NB, 256, 0, stream>>>(cnt, bsum);
    scan_bases<<<1, 256, 0, stream>>>(bsum, row_off);
    scan_write<<<SCAN_NB, 256, 0, stream>>>(cnt, bsum, row_off);
    gemm_scatter<<<GEMM_BLOCKS + EG_BLOCKS, 256, 0, stream>>>(
        x, wpack, scale, bias, mapped, s1, s2, src, dst, cnt, rank, dst_sorted);
    node_aggregate<<<(N_NODES + 3) / 4, 256, 0, stream>>>(row_off, dst_sorted,
                                                          s1, s2,
                                                          (const unsigned int*)mapped,
                                                          out);
}

// Round 17
// 269.549 us; speedup vs baseline: 1.1893x; 1.1893x over previous
//
#include <hip/hip_runtime.h>
#include <math.h>

#define N_NODES 100000
#define D 128
#define N_EDGES 1600000
#define BN_EPS 1e-5f
#define SCAN_NB 200
#define SCAN_BC 500    // elements per scan block; 200*500 = 100000 exact
#define EG_BLOCKS 1563 // ceil(N_EDGES / 1024); hist & scatter: 4 edges/thread
#define GEMM_BLOCKS 1563 // ceil(N_NODES / 64)
#define STATS_BLOCKS 1024
#define NCOPY 8

typedef __attribute__((ext_vector_type(8))) short bf16x8;
typedef __attribute__((ext_vector_type(4))) float f32x4;

__device__ inline unsigned short f2bf(float f) {
    unsigned int u = __float_as_uint(f);
    unsigned int r = u + 0x7FFFu + ((u >> 16) & 1u);
    return (unsigned short)(r >> 16);
}
__device__ inline float bf2f(unsigned short b) {
    return __uint_as_float(((unsigned int)b) << 16);
}

// ============ FUSED: bn_stats (blocks 0..1023) || hist_rank (1024..2586) ===========
// bn_stats fixed per R16 post-mortem: the ~135us pole was stats' ROLLED load loop
// (1 load in flight, VALUBusy 1.3%), not the hist atomics. Now 1024 blocks and
// 8-batch phase-separated loads (8 independent loads issued before any use), with
// fire-and-forget atomic partials into 8 copies (no same-line pileup).
__global__ __launch_bounds__(256)
void stats_hist(const float* __restrict__ x, float* __restrict__ sums_part,
                const int* __restrict__ src, int* __restrict__ cnt,
                int* __restrict__ rank) {
    if (blockIdx.x < STATS_BLOCKS) {
        const int col  = threadIdx.x & 127;
        const int half = threadIdx.x >> 7;
        const int STRIDE = STATS_BLOCKS * 2;   // 2048 rows
        float s = 0.f, sq = 0.f;
        int r = blockIdx.x * 2 + half;
        for (; r + 7 * STRIDE < N_NODES; r += 8 * STRIDE) {
            float v[8];
#pragma unroll
            for (int q = 0; q < 8; ++q)
                v[q] = x[(size_t)(r + q * STRIDE) * D + col];
#pragma unroll
            for (int q = 0; q < 8; ++q) { s += v[q]; sq += v[q] * v[q]; }
        }
        for (; r < N_NODES; r += STRIDE) {
            float v = x[(size_t)r * D + col];
            s += v; sq += v * v;
        }
        __shared__ float ls[2][128];
        __shared__ float lq[2][128];
        ls[half][col] = s; lq[half][col] = sq;
        __syncthreads();
        if (threadIdx.x < 128) {
            float* part = sums_part + (size_t)(blockIdx.x & 7) * 256;
            atomicAdd(&part[col],       ls[0][col] + ls[1][col]);
            atomicAdd(&part[128 + col], lq[0][col] + lq[1][col]);
        }
    } else {
        const int b = blockIdx.x - STATS_BLOCKS;
        int* c = cnt + (size_t)(b & (NCOPY - 1)) * N_NODES;
        const int base = b * 1024 + threadIdx.x;
#pragma unroll
        for (int k = 0; k < 4; ++k) {
            int i = base + k * 256;
            if (i < N_EDGES) rank[i] = atomicAdd(&c[src[i]], 1);
        }
    }
}

// ============ FUSED: bn_finalize (block 0) || pack_weights (blocks 1..24) ==========
__global__ __launch_bounds__(256)
void finalize_pack(const float* __restrict__ sums_part, const float* __restrict__ gamma,
                   const float* __restrict__ beta, float* __restrict__ scale,
                   float* __restrict__ bias,
                   const float* __restrict__ k0, const float* __restrict__ k1,
                   const float* __restrict__ k2, unsigned short* __restrict__ wpack) {
    if (blockIdx.x == 0) {
        if (threadIdx.x < 128) {
            int c = threadIdx.x;
            float sum = 0.f, sumsq = 0.f;
#pragma unroll
            for (int p = 0; p < 8; ++p) {
                sum   += sums_part[p * 256 + c];
                sumsq += sums_part[p * 256 + 128 + c];
            }
            float mean = sum * (1.0f / N_NODES);
            float var  = sumsq * (1.0f / N_NODES) - mean * mean;
            float rstd = rsqrtf(var + BN_EPS);
            float sc = gamma[c] * rstd;
            scale[c] = sc;
            bias[c]  = beta[c] - mean * sc;
        }
        return;
    }
    int idx = (blockIdx.x - 1) * 256 + threadIdx.x;   // one 8-elem fragment each
    if (idx >= 3 * 4 * 8 * 64) return;                // 6144
    int m    = idx >> 11;
    int r    = idx & 2047;
    int kk   = r >> 9;
    int r2   = r & 511;
    int nt   = r2 >> 6;
    int lane = r2 & 63;
    const float* W = (m == 0) ? k0 : (m == 1) ? k1 : k2;
    int col   = nt * 16 + (lane & 15);
    int kbase = kk * 32 + (lane >> 4) * 8;
    unsigned int wh[4], wl[4];
#pragma unroll
    for (int i = 0; i < 4; ++i) {
        float a = W[(kbase + 2 * i)     * 128 + col];
        float b = W[(kbase + 2 * i + 1) * 128 + col];
        unsigned short ah = f2bf(a), bh = f2bf(b);
        unsigned short al = f2bf(a - bf2f(ah)), bl = f2bf(b - bf2f(bh));
        wh[i] = (unsigned int)ah | ((unsigned int)bh << 16);
        wl[i] = (unsigned int)al | ((unsigned int)bl << 16);
    }
    uint4* outp = (uint4*)wpack;
    outp[idx]        = make_uint4(wh[0], wh[1], wh[2], wh[3]);
    outp[6144 + idx] = make_uint4(wl[0], wl[1], wl[2], wl[3]);
}

// ---------------- hierarchical scan, phase A: per-block sums over 8 copies ---------
__global__ __launch_bounds__(256)
void scan_blocksum(const int* __restrict__ cnt, int* __restrict__ bsum) {
    __shared__ int red[256];
    const int b = blockIdx.x, t = threadIdx.x;
    const int base = b * SCAN_BC;
    int s = 0;
    for (int i = t; i < SCAN_BC; i += 256) {
        int node = base + i;
#pragma unroll
        for (int x = 0; x < 8; ++x) s += cnt[(size_t)x * N_NODES + node];
    }
    red[t] = s;
    __syncthreads();
    for (int off = 128; off; off >>= 1) {
        if (t < off) red[t] += red[t + off];
        __syncthreads();
    }
    if (t == 0) bsum[b] = red[0];
}

// ---------------- phase B: exclusive scan of the 200 block sums ----------------
__global__ __launch_bounds__(256)
void scan_bases(int* __restrict__ bsum, int* __restrict__ row_off) {
    __shared__ int v[256];
    const int t = threadIdx.x;
    v[t] = (t < SCAN_NB) ? bsum[t] : 0;
    __syncthreads();
    for (int off = 1; off < 256; off <<= 1) {
        int u = (t >= off) ? v[t - off] : 0;
        __syncthreads();
        v[t] += u;
        __syncthreads();
    }
    if (t < SCAN_NB) bsum[t] = (t == 0) ? 0 : v[t - 1];
    if (t == 0) row_off[N_NODES] = v[SCAN_NB - 1];
}

// ---------------- phase C: scan + write row_off; rewrite cnt[x][s] -> segment base -
__global__ __launch_bounds__(256)
void scan_write(int* __restrict__ cnt, const int* __restrict__ bsum,
                int* __restrict__ row_off) {
    __shared__ int tsum[256];
    const int b = blockIdx.x, t = threadIdx.x;
    const int i0 = b * SCAN_BC + t * 2;   // t < 250 covers the 500-elem chunk
    int c0[8], c1[8];
    int tot0 = 0, tot1 = 0;
    if (t < 250) {
#pragma unroll
        for (int x = 0; x < 8; ++x) {
            c0[x] = cnt[(size_t)x * N_NODES + i0];
            c1[x] = cnt[(size_t)x * N_NODES + i0 + 1];
            tot0 += c0[x]; tot1 += c1[x];
        }
    }
    tsum[t] = tot0 + tot1;
    __syncthreads();
    for (int off = 1; off < 256; off <<= 1) {
        int u = (t >= off) ? tsum[t - off] : 0;
        __syncthreads();
        tsum[t] += u;
        __syncthreads();
    }
    if (t < 250) {
        int run = bsum[b] + ((t == 0) ? 0 : tsum[t - 1]);
        row_off[i0] = run;
        int acc = run;
#pragma unroll
        for (int x = 0; x < 8; ++x) { cnt[(size_t)x * N_NODES + i0] = acc; acc += c0[x]; }
        run += tot0;
        row_off[i0 + 1] = run;
        acc = run;
#pragma unroll
        for (int x = 0; x < 8; ++x) { cnt[(size_t)x * N_NODES + i0 + 1] = acc; acc += c1[x]; }
    }
}

// ============ FUSED: gemm_mfma (blocks 0..1562) || scatter_edges (1563..) ==========
// scatter copy selector: b&7 == (i>>10)&7, matching the 1024-edge hist windows.
__global__ __launch_bounds__(256, 4)
void gemm_scatter(const float* __restrict__ x, const unsigned short* __restrict__ wpack,
                  const float* __restrict__ scale, const float* __restrict__ bias,
                  unsigned short* __restrict__ mapped, float* __restrict__ s1,
                  float* __restrict__ s2,
                  const int* __restrict__ src, const int* __restrict__ dst,
                  const int* __restrict__ cnt, const int* __restrict__ rank,
                  int* __restrict__ dst_sorted) {
    __shared__ unsigned short xbuf[64 * 128];   // 16 KB, XOR-swizzled rows
    if (blockIdx.x >= GEMM_BLOCKS) {
        // ---- scatter path (atomic-free) ----
        const int b = blockIdx.x - GEMM_BLOCKS;
        const int* c = cnt + (size_t)(b & (NCOPY - 1)) * N_NODES;
        const int base = b * 1024 + threadIdx.x;
#pragma unroll
        for (int k = 0; k < 4; ++k) {
            int i = base + k * 256;
            if (i < N_EDGES) dst_sorted[c[src[i]] + rank[i]] = dst[i];
        }
        return;
    }
    // ---- gemm path (R10-proven: time-shared 16KB LDS, 3 barriers) ----
    const int tid  = threadIdx.x;
    const int wave = tid >> 6, lane = tid & 63;
    const int base = blockIdx.x * 64;
    char* xb = (char*)xbuf;

    float2 sc = ((const float2*)scale)[lane];
    float2 bs = ((const float2*)bias)[lane];

    // phase 1: stage LO into LDS; keep HI packed in registers
    unsigned int hipack[16];
#pragma unroll
    for (int rr = 0; rr < 16; ++rr) {
        int row  = wave * 16 + rr;
        int node = base + row;
        float2 v = make_float2(0.f, 0.f);
        if (node < N_NODES) v = ((const float2*)x)[(size_t)node * 64 + lane];
        float f0 = v.x * sc.x + bs.x;
        float f1 = v.y * sc.y + bs.y;
        unsigned short h0 = f2bf(f0), h1 = f2bf(f1);
        unsigned short l0 = f2bf(f0 - bf2f(h0)), l1 = f2bf(f1 - bf2f(h1));
        hipack[rr] = (unsigned int)h0 | ((unsigned int)h1 << 16);
        int byte = (row * 256 + lane * 4) ^ ((row & 7) << 4);
        *(unsigned int*)(xb + byte) = (unsigned int)l0 | ((unsigned int)l1 << 16);
    }
    __syncthreads();   // W_lo -> R_lo (cross-lane RAW)

    const int arow  = wave * 16 + (lane & 15);
    const int lrow0 = wave * 16 + (lane >> 4) * 4;

    bf16x8 al[4];
#pragma unroll
    for (int kk = 0; kk < 4; ++kk) {
        int byte = (arow * 256 + kk * 64 + (lane >> 4) * 16) ^ ((arow & 7) << 4);
        al[kk] = *(const bf16x8*)(xb + byte);
    }
    unsigned int xlo[16];
#pragma unroll
    for (int nt = 0; nt < 8; ++nt) {
#pragma unroll
        for (int reg = 0; reg < 4; ++reg) {
            int lrow = lrow0 + reg;
            int col  = nt * 16 + (lane & 15);
            int byte = (lrow * 256 + col * 2) ^ ((lrow & 7) << 4);
            unsigned short v = *(const unsigned short*)(xb + byte);
            int idx = nt * 4 + reg;
            if (idx & 1) xlo[idx >> 1] |= ((unsigned int)v) << 16;
            else         xlo[idx >> 1]  = v;
        }
    }
    __syncthreads();   // R_lo -> W_hi (cross-lane WAR)

    // phase 2: overwrite LDS slice with HI
#pragma unroll
    for (int rr = 0; rr < 16; ++rr) {
        int row  = wave * 16 + rr;
        int byte = (row * 256 + lane * 4) ^ ((row & 7) << 4);
        *(unsigned int*)(xb + byte) = hipack[rr];
    }
    __syncthreads();   // W_hi -> R_hi (cross-lane RAW)

    bf16x8 ah[4];
#pragma unroll
    for (int kk = 0; kk < 4; ++kk) {
        int byte = (arow * 256 + kk * 64 + (lane >> 4) * 16) ^ ((arow & 7) << 4);
        ah[kk] = *(const bf16x8*)(xb + byte);
    }

    const bf16x8* wp = (const bf16x8*)wpack;   // hi: [0,6144) frags; lo: +6144

    // matrix 0 -> mapped (hi-only precision, bf16 store)
    {
        f32x4 acc[8] = {};
#pragma unroll
        for (int kk = 0; kk < 4; ++kk) {
#pragma unroll
            for (int nt = 0; nt < 8; ++nt) {
                bf16x8 b = wp[(kk * 8 + nt) * 64 + lane];
                acc[nt] = __builtin_amdgcn_mfma_f32_16x16x32_bf16(ah[kk], b, acc[nt], 0, 0, 0);
            }
        }
        int crow = base + wave * 16 + (lane >> 4) * 4;
        int ccol = lane & 15;
#pragma unroll
        for (int nt = 0; nt < 8; ++nt) {
#pragma unroll
            for (int reg = 0; reg < 4; ++reg) {
                int node = crow + reg;
                if (node < N_NODES)
                    mapped[(size_t)node * 128 + nt * 16 + ccol] = f2bf(acc[nt][reg]);
            }
        }
    }

    // matrices 1,2 (split precision) -> per-row dot with xn -> s1,s2
    {
        float p1[4] = {0.f, 0.f, 0.f, 0.f};
        float p2[4] = {0.f, 0.f, 0.f, 0.f};
#pragma unroll
        for (int nt = 0; nt < 8; ++nt) {
            f32x4 a1 = {0.f, 0.f, 0.f, 0.f};
            f32x4 a2 = {0.f, 0.f, 0.f, 0.f};
#pragma unroll
            for (int kk = 0; kk < 4; ++kk) {
                int fi = (kk * 8 + nt) * 64 + lane;
                bf16x8 b1h = wp[2048 * 1 + fi];
                bf16x8 b1l = wp[6144 + 2048 * 1 + fi];
                bf16x8 b2h = wp[2048 * 2 + fi];
                bf16x8 b2l = wp[6144 + 2048 * 2 + fi];
                a1 = __builtin_amdgcn_mfma_f32_16x16x32_bf16(ah[kk], b1h, a1, 0, 0, 0);
                a1 = __builtin_amdgcn_mfma_f32_16x16x32_bf16(al[kk], b1h, a1, 0, 0, 0);
                a1 = __builtin_amdgcn_mfma_f32_16x16x32_bf16(ah[kk], b1l, a1, 0, 0, 0);
                a2 = __builtin_amdgcn_mfma_f32_16x16x32_bf16(ah[kk], b2h, a2, 0, 0, 0);
                a2 = __builtin_amdgcn_mfma_f32_16x16x32_bf16(al[kk], b2h, a2, 0, 0, 0);
                a2 = __builtin_amdgcn_mfma_f32_16x16x32_bf16(ah[kk], b2l, a2, 0, 0, 0);
            }
            int col = nt * 16 + (lane & 15);
#pragma unroll
            for (int reg = 0; reg < 4; ++reg) {
                int lrow = lrow0 + reg;
                int byte = (lrow * 256 + col * 2) ^ ((lrow & 7) << 4);
                float xh = bf2f(*(const unsigned short*)(xb + byte));
                int idx = nt * 4 + reg;
                unsigned short lo16 = (idx & 1) ? (unsigned short)(xlo[idx >> 1] >> 16)
                                                : (unsigned short)(xlo[idx >> 1] & 0xFFFFu);
                float xv = xh + bf2f(lo16);
                p1[reg] = fmaf(a1[reg], xv, p1[reg]);
                p2[reg] = fmaf(a2[reg], xv, p2[reg]);
            }
        }
#pragma unroll
        for (int reg = 0; reg < 4; ++reg) {
#pragma unroll
            for (int off = 1; off < 16; off <<= 1) {
                p1[reg] += __shfl_xor(p1[reg], off);
                p2[reg] += __shfl_xor(p2[reg], off);
            }
        }
        if ((lane & 15) == 0) {
            int nbase = base + wave * 16 + (lane >> 4) * 4;
#pragma unroll
            for (int reg = 0; reg < 4; ++reg) {
                int node = nbase + reg;
                if (node < N_NODES) {
                    s1[node] = tanhf(p1[reg]);
                    s2[node] = tanhf(p2[reg]);
                }
            }
        }
    }
}

// ---------------- per-node (1 wave): inline score + softmax + gather + relu --------
__global__ __launch_bounds__(256)
void node_aggregate(const int* __restrict__ row_off, const int* __restrict__ dst_sorted,
                    const float* __restrict__ s1, const float* __restrict__ s2,
                    const unsigned int* __restrict__ mapped,
                    float* __restrict__ out) {
    const int wave = threadIdx.x >> 6, lane = threadIdx.x & 63;
    const int n = blockIdx.x * 4 + wave;
    if (n >= N_NODES) return;
    const int beg = row_off[n], end = row_off[n + 1];
    const int deg = end - beg;
    float acc0 = 0.f, acc1 = 0.f, den = 0.f;

#define GATHER8(WSRC, DSRC, J)                                                   \
    {                                                                            \
        float w0 = __shfl(WSRC, (J) + 0), w1 = __shfl(WSRC, (J) + 1);            \
        float w2 = __shfl(WSRC, (J) + 2), w3 = __shfl(WSRC, (J) + 3);            \
        float w4 = __shfl(WSRC, (J) + 4), w5 = __shfl(WSRC, (J) + 5);            \
        float w6 = __shfl(WSRC, (J) + 6), w7 = __shfl(WSRC, (J) + 7);            \
        int d0 = __shfl(DSRC, (J) + 0), d1 = __shfl(DSRC, (J) + 1);              \
        int d2 = __shfl(DSRC, (J) + 2), d3 = __shfl(DSRC, (J) + 3);              \
        int d4 = __shfl(DSRC, (J) + 4), d5 = __shfl(DSRC, (J) + 5);              \
        int d6 = __shfl(DSRC, (J) + 6), d7 = __shfl(DSRC, (J) + 7);              \
        unsigned int m0 = mapped[(size_t)d0 * 64 + lane];                        \
        unsigned int m1 = mapped[(size_t)d1 * 64 + lane];                        \
        unsigned int m2 = mapped[(size_t)d2 * 64 + lane];                        \
        unsigned int m3 = mapped[(size_t)d3 * 64 + lane];                        \
        unsigned int m4 = mapped[(size_t)d4 * 64 + lane];                        \
        unsigned int m5 = mapped[(size_t)d5 * 64 + lane];                        \
        unsigned int m6 = mapped[(size_t)d6 * 64 + lane];                        \
        unsigned int m7 = mapped[(size_t)d7 * 64 + lane];                        \
        acc0 = fmaf(w0, bf2f((unsigned short)(m0 & 0xFFFFu)), acc0);             \
        acc1 = fmaf(w0, bf2f((unsigned short)(m0 >> 16)), acc1);                 \
        acc0 = fmaf(w1, bf2f((unsigned short)(m1 & 0xFFFFu)), acc0);             \
        acc1 = fmaf(w1, bf2f((unsigned short)(m1 >> 16)), acc1);                 \
        acc0 = fmaf(w2, bf2f((unsigned short)(m2 & 0xFFFFu)), acc0);             \
        acc1 = fmaf(w2, bf2f((unsigned short)(m2 >> 16)), acc1);                 \
        acc0 = fmaf(w3, bf2f((unsigned short)(m3 & 0xFFFFu)), acc0);             \
        acc1 = fmaf(w3, bf2f((unsigned short)(m3 >> 16)), acc1);                 \
        acc0 = fmaf(w4, bf2f((unsigned short)(m4 & 0xFFFFu)), acc0);             \
        acc1 = fmaf(w4, bf2f((unsigned short)(m4 >> 16)), acc1);                 \
        acc0 = fmaf(w5, bf2f((unsigned short)(m5 & 0xFFFFu)), acc0);             \
        acc1 = fmaf(w5, bf2f((unsigned short)(m5 >> 16)), acc1);                 \
        acc0 = fmaf(w6, bf2f((unsigned short)(m6 & 0xFFFFu)), acc0);             \
        acc1 = fmaf(w6, bf2f((unsigned short)(m6 >> 16)), acc1);                 \
        acc0 = fmaf(w7, bf2f((unsigned short)(m7 & 0xFFFFu)), acc0);             \
        acc1 = fmaf(w7, bf2f((unsigned short)(m7 >> 16)), acc1);                 \
    }

    if (deg > 0 && deg <= 64) {
        float s1n = s1[n];
        int   d_l = 0; float e_l = -INFINITY;
        if (lane < deg) {
            d_l = dst_sorted[beg + lane];
            float v = s1n + s2[d_l];
            e_l = v > 0.f ? v : 0.01f * v;
        }
        float m = e_l;
#pragma unroll
        for (int off = 1; off < 64; off <<= 1) m = fmaxf(m, __shfl_xor(m, off));
        float w_l = (lane < deg) ? expf(e_l - m) : 0.f;
        den = w_l;
        int j = 0;
        for (; j + 8 <= deg; j += 8) GATHER8(w_l, d_l, j)
        for (; j < deg; ++j) {
            float wj = __shfl(w_l, j);
            int   dj = __shfl(d_l, j);
            unsigned int mv = mapped[(size_t)dj * 64 + lane];
            acc0 = fmaf(wj, bf2f((unsigned short)(mv & 0xFFFFu)), acc0);
            acc1 = fmaf(wj, bf2f((unsigned short)(mv >> 16)), acc1);
        }
    } else if (deg > 64) {
        float s1n = s1[n];
        float m = -INFINITY;
        for (int chunk = beg; chunk < end; chunk += 64) {
            if (chunk + lane < end) {
                int dj = dst_sorted[chunk + lane];
                float v = s1n + s2[dj];
                m = fmaxf(m, v > 0.f ? v : 0.01f * v);
            }
        }
#pragma unroll
        for (int off = 1; off < 64; off <<= 1) m = fmaxf(m, __shfl_xor(m, off));
        for (int chunk = beg; chunk < end; chunk += 64) {
            int nc = min(64, end - chunk);
            int   d_l = 0; float w_l = 0.f;
            if (lane < nc) {
                d_l = dst_sorted[chunk + lane];
                float v = s1n + s2[d_l];
                float e = v > 0.f ? v : 0.01f * v;
                w_l = expf(e - m);
            }
            den += w_l;
            int j = 0;
            for (; j + 8 <= nc; j += 8) GATHER8(w_l, d_l, j)
            for (; j < nc; ++j) {
                float wj = __shfl(w_l, j);
                int   dj = __shfl(d_l, j);
                unsigned int mv = mapped[(size_t)dj * 64 + lane];
                acc0 = fmaf(wj, bf2f((unsigned short)(mv & 0xFFFFu)), acc0);
                acc1 = fmaf(wj, bf2f((unsigned short)(mv >> 16)), acc1);
            }
        }
    }
#undef GATHER8

    if (deg > 0) {
#pragma unroll
        for (int off = 1; off < 64; off <<= 1) den += __shfl_xor(den, off);
        float inv = 1.f / fmaxf(den, 1e-16f);
        acc0 *= inv; acc1 *= inv;
    }
    ((float2*)out)[(size_t)n * 64 + lane] = make_float2(fmaxf(acc0, 0.f), fmaxf(acc1, 0.f));
}

extern "C" void kernel_launch(void* const* d_in, const int* in_sizes, int n_in,
                              void* d_out, int out_size, void* d_ws, size_t ws_size,
                              hipStream_t stream) {
    const float* x     = (const float*)d_in[0];
    const int*   ei    = (const int*)d_in[1];   // [2][E]: row0 = src, row1 = dst
    const float* k0    = (const float*)d_in[2];
    const float* k1    = (const float*)d_in[3];
    const float* k2    = (const float*)d_in[4];
    const float* gamma = (const float*)d_in[5];
    const float* beta  = (const float*)d_in[6];
    float* out = (float*)d_out;

    const int* src = ei;
    const int* dst = ei + N_EDGES;

    char* ws = (char*)d_ws;
    unsigned short* wpack = (unsigned short*)ws;           ws += 6 * 128 * 128 * 2; // hi+lo
    float* s1       = (float*)ws;                          ws += N_NODES * 4;
    float* s2       = (float*)ws;                          ws += N_NODES * 4;
    float* scale    = (float*)ws;                          ws += 128 * 4;
    float* bias     = (float*)ws;                          ws += 128 * 4;
    float* sums_part = (float*)ws;                         ws += 8 * 256 * 4;
    int*   bsum     = (int*)ws;                            ws += 256 * 4;
    int*   row_off  = (int*)ws;                            ws += (N_NODES + 1) * 4;
    int*   cnt      = (int*)ws;                            ws += (size_t)NCOPY * N_NODES * 4;
    int*   rank     = (int*)ws;                            ws += (size_t)N_EDGES * 4;
    int*   dst_sorted = (int*)ws;                          ws += (size_t)N_EDGES * 4;
    unsigned short* mapped = (unsigned short*)ws;          ws += (size_t)N_NODES * D * 2;

    // zero accumulators (harness does not re-poison between replays)
    hipMemsetAsync(sums_part, 0, 8 * 256 * sizeof(float), stream);
    hipMemsetAsync(cnt, 0, (size_t)NCOPY * N_NODES * sizeof(int), stream);

    stats_hist<<<STATS_BLOCKS + EG_BLOCKS, 256, 0, stream>>>(x, sums_part, src, cnt,
                                                             rank);
    finalize_pack<<<25, 256, 0, stream>>>(sums_part, gamma, beta, scale, bias,
                                          k0, k1, k2, wpack);
    scan_blocksum<<<SCAN_NB, 256, 0, stream>>>(cnt, bsum);
    scan_bases<<<1, 256, 0, stream>>>(bsum, row_off);
    scan_write<<<SCAN_NB, 256, 0, stream>>>(cnt, bsum, row_off);
    gemm_scatter<<<GEMM_BLOCKS + EG_BLOCKS, 256, 0, stream>>>(
        x, wpack, scale, bias, mapped, s1, s2, src, dst, cnt, rank, dst_sorted);
    node_aggregate<<<(N_NODES + 3) / 4, 256, 0, stream>>>(row_off, dst_sorted,
                                                          s1, s2,
                                                          (const unsigned int*)mapped,
                                                          out);
}